// Round 1
// baseline (2108.008 us; speedup 1.0000x reference)
//
#include <hip/hip_runtime.h>
#include <hip/hip_cooperative_groups.h>

namespace cg = cooperative_groups;

typedef __attribute__((ext_vector_type(8))) short short8;
typedef __attribute__((ext_vector_type(4))) float float4v;
typedef __attribute__((ext_vector_type(4))) unsigned short ushort4v;

#define DEV __device__ __forceinline__

DEV unsigned short f2bf(float f) {
  union { float f; unsigned u; } v; v.f = f;
  unsigned r = v.u + 0x7fffu + ((v.u >> 16) & 1u);
  return (unsigned short)(r >> 16);
}
DEV float bf2f(unsigned short h) {
  union { unsigned u; float f; } v; v.u = ((unsigned)h) << 16;
  return v.f;
}

// async global->LDS, 16B per lane; LDS dest is wave-uniform base + lane*16
DEV void gl2lds16(const void* g, void* l) {
  __builtin_amdgcn_global_load_lds(
      (const __attribute__((address_space(1))) void*)g,
      (__attribute__((address_space(3))) void*)l, 16, 0, 0);
}

// ---------------------------------------------------------------------------
// fp32 -> bf16 convert, 4 elems/thread
__global__ __launch_bounds__(256) void cvt4(const float* __restrict__ in,
                                            unsigned short* __restrict__ out, int n4) {
  const int idx = blockIdx.x * 256 + threadIdx.x;
  if (idx >= n4) return;
  float4 v = ((const float4*)in)[idx];
  ushort4v o = { f2bf(v.x), f2bf(v.y), f2bf(v.z), f2bf(v.w) };
  ((ushort4v*)out)[idx] = o;
}

// ---------------------------------------------------------------------------
// Gather X[row] = [emb(kw_{i+1}) | emb(lw_i)] as bf16, row = i*32+b
__global__ __launch_bounds__(256) void gatherx(const float* __restrict__ emb,
                                               const int* __restrict__ targets,
                                               const int* __restrict__ tkws,
                                               unsigned short* __restrict__ X) {
  const int row = blockIdx.x;
  const int i = row >> 5, b = row & 31;
  const int t = threadIdx.x;
  const int kw = tkws[b * 64 + i + 1];
  const int lw = targets[b * 64 + i];
  const float4* src = (t < 128) ? (const float4*)(emb + (size_t)kw * 512)
                                : (const float4*)(emb + (size_t)lw * 512);
  const int c = t & 127;
  float4 v = src[c];
  ushort4v o = { f2bf(v.x), f2bf(v.y), f2bf(v.z), f2bf(v.w) };
  ((ushort4v*)(X + (size_t)row * 1024))[(t < 128 ? 0 : 128) + c] = o;
}

// ---------------------------------------------------------------------------
// C = A[M,1024] * B[N,1024]^T, 128x128 tile, BK=32, bf16 MFMA 16x16x32.
// EPI=0: store fp32 C (ldc = ldc_or_nvt).
// EPI=1: add bias, per-row (max, sum-exp) over this 128-col tile -> partials.
template <int EPI>
__global__ __launch_bounds__(256, 1) void gemm_bt(
    const unsigned short* __restrict__ A,
    const unsigned short* __restrict__ B,
    float* __restrict__ out,
    const float* __restrict__ bias,
    int ldc_or_nvt) {
  __shared__ __align__(16) unsigned short As[128 * 32];
  __shared__ __align__(16) unsigned short Bs[128 * 32];
  __shared__ float ms[2][128][2];
  const int tid = threadIdx.x;
  const int w = tid >> 6, lane = tid & 63;
  const int r4 = lane >> 2, c4 = lane & 3;
  const int m0 = blockIdx.x * 128, n0 = blockIdx.y * 128;
  const int m_off = (w & 1) * 64, n_off = (w >> 1) * 64;
  const int lrow = lane & 15, lk = (lane >> 4) * 8;

  const unsigned short* Ab = A + (size_t)(m0 + w * 16 + r4) * 1024 + c4 * 8;
  const unsigned short* Bb = B + (size_t)(n0 + w * 16 + r4) * 1024 + c4 * 8;

  float4v acc[4][4] = {};

  for (int k0 = 0; k0 < 1024; k0 += 32) {
    gl2lds16(Ab + k0,             &As[w * 512]);
    gl2lds16(Ab + 64 * 1024 + k0, &As[2048 + w * 512]);
    gl2lds16(Bb + k0,             &Bs[w * 512]);
    gl2lds16(Bb + 64 * 1024 + k0, &Bs[2048 + w * 512]);
    __syncthreads();
    short8 af[4], bfr[4];
#pragma unroll
    for (int t = 0; t < 4; t++) {
      af[t]  = *(const short8*)&As[(m_off + t * 16 + lrow) * 32 + lk];
      bfr[t] = *(const short8*)&Bs[(n_off + t * 16 + lrow) * 32 + lk];
    }
#pragma unroll
    for (int mt = 0; mt < 4; mt++)
#pragma unroll
      for (int nt = 0; nt < 4; nt++)
        acc[mt][nt] = __builtin_amdgcn_mfma_f32_16x16x32_bf16(af[mt], bfr[nt], acc[mt][nt], 0, 0, 0);
    __syncthreads();
  }

  if constexpr (EPI == 0) {
    const int ldc = ldc_or_nvt;
#pragma unroll
    for (int mt = 0; mt < 4; mt++) {
      const int gr = m0 + m_off + mt * 16 + (lane >> 4) * 4;
#pragma unroll
      for (int nt = 0; nt < 4; nt++) {
        const int gc = n0 + n_off + nt * 16 + lrow;
#pragma unroll
        for (int rg = 0; rg < 4; rg++)
          out[(size_t)(gr + rg) * ldc + gc] = acc[mt][nt][rg];
      }
    }
  } else {
    const int nvt = ldc_or_nvt;
    float b4[4];
#pragma unroll
    for (int nt = 0; nt < 4; nt++) b4[nt] = bias[n0 + n_off + nt * 16 + lrow];
#pragma unroll
    for (int mt = 0; mt < 4; mt++) {
#pragma unroll
      for (int rg = 0; rg < 4; rg++) {
        float v0 = acc[mt][0][rg] + b4[0];
        float v1 = acc[mt][1][rg] + b4[1];
        float v2 = acc[mt][2][rg] + b4[2];
        float v3 = acc[mt][3][rg] + b4[3];
        float mx = fmaxf(fmaxf(v0, v1), fmaxf(v2, v3));
#pragma unroll
        for (int d = 1; d < 16; d <<= 1) mx = fmaxf(mx, __shfl_xor(mx, d, 64));
        float s = __expf(v0 - mx) + __expf(v1 - mx) + __expf(v2 - mx) + __expf(v3 - mx);
#pragma unroll
        for (int d = 1; d < 16; d <<= 1) s += __shfl_xor(s, d, 64);
        if ((lane & 15) == 0) {
          int r = m_off + mt * 16 + (lane >> 4) * 4 + rg;
          ms[w >> 1][r][0] = mx;
          ms[w >> 1][r][1] = s;
        }
      }
    }
    __syncthreads();
    if (tid < 128) {
      float m1 = ms[0][tid][0], s1 = ms[0][tid][1];
      float m2 = ms[1][tid][0], s2 = ms[1][tid][1];
      float M = fmaxf(m1, m2);
      float S = s1 * __expf(m1 - M) + s2 * __expf(m2 - M);
      ((float2*)out)[(size_t)(m0 + tid) * nvt + blockIdx.y] = make_float2(M, S);
    }
  }
}

// ---------------------------------------------------------------------------
// Cooperative recurrence: 64 wgs x 256 thr, wg owns 16 hidden cols (jb..jb+15).
// Per step: gh = h @ Whh^T via MFMA (waves split (khalf, mtile)), gates in fp32,
// write wh -> WH (bf16) and h state. Rare EOS path runs the sentence GRU.
__global__ __launch_bounds__(256, 1) void recur_kernel(
    const float* __restrict__ Gi,
    const unsigned short* __restrict__ WhhB,
    const unsigned short* __restrict__ sWihB,
    const unsigned short* __restrict__ sWhhB,
    unsigned short* __restrict__ h_bf,
    unsigned short* __restrict__ sent_bf,
    unsigned short* __restrict__ WH,
    const float* __restrict__ w_bih, const float* __restrict__ w_bhh,
    const float* __restrict__ s_bih, const float* __restrict__ s_bhh,
    const int* __restrict__ targets,
    const float* __restrict__ sent_state) {
  cg::grid_group grid = cg::this_grid();
  __shared__ float Cred[2][32][48];
  __shared__ float hsl[32][16];
  __shared__ float ssl[32][16];
  __shared__ float whsl[32][16];
  const int tid = threadIdx.x;
  const int lane = tid & 63, wv = tid >> 6;
  const int khalf = wv >> 1, mtile = wv & 1;
  const int jb = blockIdx.x * 16;
  const int bb = mtile * 16 + (lane & 15);
  const int kb = khalf * 512 + (lane >> 4) * 8;

  for (int u = tid; u < 512; u += 256) {
    int b = u >> 4, jj = u & 15;
    float v = sent_state[b * 1024 + jb + jj];
    hsl[b][jj] = v;
    ssl[b][jj] = v;
    unsigned short bv = f2bf(v);
    h_bf[b * 1024 + jb + jj] = bv;
    sent_bf[b * 1024 + jb + jj] = bv;
  }
  __threadfence();
  grid.sync();
  __threadfence();

  for (int i = 0; i < 63; i++) {
    const bool anyeos = __any(targets[(lane & 31) * 64 + i + 1] == 1);

    float4v acc[3] = {};
#pragma unroll
    for (int ks = 0; ks < 16; ks++) {
      short8 a = *(const short8*)&h_bf[bb * 1024 + kb + ks * 32];
#pragma unroll
      for (int g = 0; g < 3; g++) {
        short8 b8 = *(const short8*)&WhhB[(size_t)(g * 1024 + jb + (lane & 15)) * 1024 + kb + ks * 32];
        acc[g] = __builtin_amdgcn_mfma_f32_16x16x32_bf16(a, b8, acc[g], 0, 0, 0);
      }
    }
#pragma unroll
    for (int g = 0; g < 3; g++)
#pragma unroll
      for (int rg = 0; rg < 4; rg++)
        Cred[khalf][mtile * 16 + (lane >> 4) * 4 + rg][g * 16 + (lane & 15)] = acc[g][rg];
    __syncthreads();

    float wh2[2];
#pragma unroll
    for (int u = 0; u < 2; u++) {
      const int idx = tid * 2 + u;
      const int b = idx >> 4, jj = idx & 15;
      const int row = i * 32 + b;
      float ghr = Cred[0][b][jj]      + Cred[1][b][jj]      + w_bhh[jb + jj];
      float ghz = Cred[0][b][16 + jj] + Cred[1][b][16 + jj] + w_bhh[1024 + jb + jj];
      float ghn = Cred[0][b][32 + jj] + Cred[1][b][32 + jj] + w_bhh[2048 + jb + jj];
      float gir = Gi[(size_t)row * 3072 + jb + jj]        + w_bih[jb + jj];
      float giz = Gi[(size_t)row * 3072 + 1024 + jb + jj] + w_bih[1024 + jb + jj];
      float gin = Gi[(size_t)row * 3072 + 2048 + jb + jj] + w_bih[2048 + jb + jj];
      float r = 1.f / (1.f + __expf(-(gir + ghr)));
      float z = 1.f / (1.f + __expf(-(giz + ghz)));
      float n = tanhf(gin + r * ghn);
      float wh = (1.f - z) * n + z * hsl[b][jj];
      WH[(size_t)row * 1024 + jb + jj] = f2bf(wh);
      whsl[b][jj] = wh;
      wh2[u] = wh;
    }

    if (!anyeos) {
#pragma unroll
      for (int u = 0; u < 2; u++) {
        const int idx = tid * 2 + u;
        const int b = idx >> 4, jj = idx & 15;
        hsl[b][jj] = wh2[u];
        h_bf[b * 1024 + jb + jj] = f2bf(wh2[u]);
      }
      __threadfence();
      grid.sync();
      __threadfence();
    } else {
      __threadfence();
      grid.sync();   // WH visible grid-wide; also block-syncs so Cred reusable
      __threadfence();
      // gi_s = wh @ sWih^T
      float4v acc2[3] = {};
#pragma unroll
      for (int ks = 0; ks < 16; ks++) {
        short8 a = *(const short8*)&WH[(size_t)(i * 32 + bb) * 1024 + kb + ks * 32];
#pragma unroll
        for (int g = 0; g < 3; g++) {
          short8 b8 = *(const short8*)&sWihB[(size_t)(g * 1024 + jb + (lane & 15)) * 1024 + kb + ks * 32];
          acc2[g] = __builtin_amdgcn_mfma_f32_16x16x32_bf16(a, b8, acc2[g], 0, 0, 0);
        }
      }
#pragma unroll
      for (int g = 0; g < 3; g++)
#pragma unroll
        for (int rg = 0; rg < 4; rg++)
          Cred[khalf][mtile * 16 + (lane >> 4) * 4 + rg][g * 16 + (lane & 15)] = acc2[g][rg];
      __syncthreads();
      float gis[2][3];
#pragma unroll
      for (int u = 0; u < 2; u++) {
        const int idx = tid * 2 + u;
        const int b = idx >> 4, jj = idx & 15;
#pragma unroll
        for (int g = 0; g < 3; g++)
          gis[u][g] = Cred[0][b][g * 16 + jj] + Cred[1][b][g * 16 + jj] + s_bih[g * 1024 + jb + jj];
      }
      __syncthreads();
      // gh_s = sent @ sWhh^T
      float4v acc3[3] = {};
#pragma unroll
      for (int ks = 0; ks < 16; ks++) {
        short8 a = *(const short8*)&sent_bf[bb * 1024 + kb + ks * 32];
#pragma unroll
        for (int g = 0; g < 3; g++) {
          short8 b8 = *(const short8*)&sWhhB[(size_t)(g * 1024 + jb + (lane & 15)) * 1024 + kb + ks * 32];
          acc3[g] = __builtin_amdgcn_mfma_f32_16x16x32_bf16(a, b8, acc3[g], 0, 0, 0);
        }
      }
#pragma unroll
      for (int g = 0; g < 3; g++)
#pragma unroll
        for (int rg = 0; rg < 4; rg++)
          Cred[khalf][mtile * 16 + (lane >> 4) * 4 + rg][g * 16 + (lane & 15)] = acc3[g][rg];
      __syncthreads();
#pragma unroll
      for (int u = 0; u < 2; u++) {
        const int idx = tid * 2 + u;
        const int b = idx >> 4, jj = idx & 15;
        float shr = Cred[0][b][jj]      + Cred[1][b][jj]      + s_bhh[jb + jj];
        float shz = Cred[0][b][16 + jj] + Cred[1][b][16 + jj] + s_bhh[1024 + jb + jj];
        float shn = Cred[0][b][32 + jj] + Cred[1][b][32 + jj] + s_bhh[2048 + jb + jj];
        float r = 1.f / (1.f + __expf(-(gis[u][0] + shr)));
        float z = 1.f / (1.f + __expf(-(gis[u][1] + shz)));
        float n = tanhf(gis[u][2] + r * shn);
        float s_old = ssl[b][jj];
        float tmp = (1.f - z) * n + z * s_old;
        bool m = (targets[b * 64 + i + 1] == 1);
        float ns = m ? tmp : s_old;
        float nw = m ? tmp : whsl[b][jj];
        ssl[b][jj] = ns;
        sent_bf[b * 1024 + jb + jj] = f2bf(ns);
        hsl[b][jj] = nw;
        h_bf[b * 1024 + jb + jj] = f2bf(nw);
      }
      __threadfence();
      grid.sync();
      __threadfence();
    }
  }
}

// ---------------------------------------------------------------------------
// Per row: y = WH[row].outW[tgt] + out_b[tgt]; lse from 250 (m,s) partials;
// term = valid * (y - lse). One wave per row.
__global__ __launch_bounds__(256) void row_loss(
    const unsigned short* __restrict__ WH,
    const unsigned short* __restrict__ outWb,
    const float* __restrict__ out_b,
    const int* __restrict__ targets,
    const int* __restrict__ targets_len,
    const float2* __restrict__ partials,
    float* __restrict__ term) {
  const int wv = threadIdx.x >> 6, lane = threadIdx.x & 63;
  const int row = blockIdx.x * 4 + wv;
  const int b = row & 31, i = row >> 5;
  const int tgt = targets[b * 64 + i + 1];
  const short8* a8 = (const short8*)(WH + (size_t)row * 1024);
  const short8* w8 = (const short8*)(outWb + (size_t)tgt * 1024);
  float s = 0.f;
#pragma unroll
  for (int c = 0; c < 2; c++) {
    short8 av = a8[lane + 64 * c];
    short8 wv8 = w8[lane + 64 * c];
#pragma unroll
    for (int j = 0; j < 8; j++)
      s += bf2f((unsigned short)av[j]) * bf2f((unsigned short)wv8[j]);
  }
#pragma unroll
  for (int d = 32; d; d >>= 1) s += __shfl_xor(s, d, 64);

  float m = -1e30f, ssum = 0.f;
  for (int vt = lane; vt < 250; vt += 64) {
    float2 pp = partials[(size_t)row * 250 + vt];
    float nm = fmaxf(m, pp.x);
    ssum = ssum * __expf(m - nm) + pp.y * __expf(pp.x - nm);
    m = nm;
  }
#pragma unroll
  for (int d = 32; d; d >>= 1) {
    float om = __shfl_xor(m, d, 64);
    float os = __shfl_xor(ssum, d, 64);
    float nm = fmaxf(m, om);
    ssum = ssum * __expf(m - nm) + os * __expf(om - nm);
    m = nm;
  }
  if (lane == 0) {
    float y = s + out_b[tgt];
    float lse = m + logf(ssum);
    float valid = (targets_len[b] > i + 1) ? 1.f : 0.f;
    term[row] = valid * (y - lse);
  }
}

__global__ void final_sum(const float* __restrict__ term, float* __restrict__ out) {
  __shared__ float red[256];
  float s = 0.f;
  for (int r = threadIdx.x; r < 2016; r += 256) s += term[r];
  red[threadIdx.x] = s;
  __syncthreads();
  for (int st = 128; st; st >>= 1) {
    if ((int)threadIdx.x < st) red[threadIdx.x] += red[threadIdx.x + st];
    __syncthreads();
  }
  if (threadIdx.x == 0) out[0] = -red[0];
}

// ---------------------------------------------------------------------------
extern "C" void kernel_launch(void* const* d_in, const int* in_sizes, int n_in,
                              void* d_out, int out_size, void* d_ws, size_t ws_size,
                              hipStream_t stream) {
  const int*   targets     = (const int*)d_in[0];
  const int*   targets_kws = (const int*)d_in[1];
  const float* sent_state  = (const float*)d_in[2];
  const int*   targets_len = (const int*)d_in[3];
  const float* emb_W       = (const float*)d_in[4];
  const float* w_Wih       = (const float*)d_in[5];
  const float* w_Whh       = (const float*)d_in[6];
  const float* w_bih       = (const float*)d_in[7];
  const float* w_bhh       = (const float*)d_in[8];
  const float* s_Wih       = (const float*)d_in[9];
  const float* s_Whh       = (const float*)d_in[10];
  const float* s_bih       = (const float*)d_in[11];
  const float* s_bhh       = (const float*)d_in[12];
  const float* out_W       = (const float*)d_in[13];
  const float* out_b       = (const float*)d_in[14];

  char* base = (char*)d_ws;
  size_t off = 0;
  auto alloc = [&](size_t bytes) -> void* {
    void* r = base + off;
    off += (bytes + 255) & ~(size_t)255;
    return r;
  };
  unsigned short* outWb   = (unsigned short*)alloc(32000ull * 1024 * 2);
  unsigned short* WihB    = (unsigned short*)alloc(3072ull * 1024 * 2);
  unsigned short* WhhB    = (unsigned short*)alloc(3072ull * 1024 * 2);
  unsigned short* sWihB   = (unsigned short*)alloc(3072ull * 1024 * 2);
  unsigned short* sWhhB   = (unsigned short*)alloc(3072ull * 1024 * 2);
  unsigned short* Xb      = (unsigned short*)alloc(2048ull * 1024 * 2);
  float*          Gi      = (float*)alloc(2048ull * 3072 * 4);
  unsigned short* WH      = (unsigned short*)alloc(2048ull * 1024 * 2);
  unsigned short* h_bf    = (unsigned short*)alloc(32ull * 1024 * 2);
  unsigned short* sent_bf = (unsigned short*)alloc(32ull * 1024 * 2);
  float2*         parts   = (float2*)alloc(2048ull * 250 * 8);
  float*          term    = (float*)alloc(2048ull * 4);

  cvt4<<<32000, 256, 0, stream>>>(out_W, outWb, 8192000);
  cvt4<<<3072, 256, 0, stream>>>(w_Wih, WihB, 786432);
  cvt4<<<3072, 256, 0, stream>>>(w_Whh, WhhB, 786432);
  cvt4<<<3072, 256, 0, stream>>>(s_Wih, sWihB, 786432);
  cvt4<<<3072, 256, 0, stream>>>(s_Whh, sWhhB, 786432);
  gatherx<<<2016, 256, 0, stream>>>(emb_W, targets, targets_kws, Xb);
  gemm_bt<0><<<dim3(16, 24), 256, 0, stream>>>(Xb, WihB, Gi, nullptr, 3072);

  void* kargs[] = { (void*)&Gi, (void*)&WhhB, (void*)&sWihB, (void*)&sWhhB,
                    (void*)&h_bf, (void*)&sent_bf, (void*)&WH,
                    (void*)&w_bih, (void*)&w_bhh, (void*)&s_bih, (void*)&s_bhh,
                    (void*)&targets, (void*)&sent_state };
  hipLaunchCooperativeKernel((void*)recur_kernel, dim3(64), dim3(256), kargs, 0, stream);

  gemm_bt<1><<<dim3(16, 250), 256, 0, stream>>>(WH, outWb, (float*)parts, out_b, 250);
  row_loss<<<504, 256, 0, stream>>>(WH, outWb, out_b, targets, targets_len, parts, term);
  final_sum<<<1, 256, 0, stream>>>(term, (float*)d_out);
}

// Round 2
// 1062.913 us; speedup vs baseline: 1.9832x; 1.9832x over previous
//
#include <hip/hip_runtime.h>
#include <hip/hip_cooperative_groups.h>

namespace cg = cooperative_groups;

typedef __attribute__((ext_vector_type(8))) short short8;
typedef __attribute__((ext_vector_type(4))) float float4v;
typedef __attribute__((ext_vector_type(4))) unsigned short ushort4v;

#define DEV __device__ __forceinline__
#define AGENT __HIP_MEMORY_SCOPE_AGENT

DEV unsigned short f2bf(float f) {
  union { float f; unsigned u; } v; v.f = f;
  unsigned r = v.u + 0x7fffu + ((v.u >> 16) & 1u);
  return (unsigned short)(r >> 16);
}
DEV float bf2f(unsigned short h) {
  union { unsigned u; float f; } v; v.u = ((unsigned)h) << 16;
  return v.f;
}

// async global->LDS, 16B per lane; LDS dest is wave-uniform base + lane*16
DEV void gl2lds16(const void* g, void* l) {
  __builtin_amdgcn_global_load_lds(
      (const __attribute__((address_space(1))) void*)g,
      (__attribute__((address_space(3))) void*)l, 16, 0, 0);
}

// --- cross-workgroup data movement: LLC write-through / bypass ------------
DEV void ast32(unsigned short* p, unsigned v) {
  __hip_atomic_store((unsigned*)p, v, __ATOMIC_RELAXED, AGENT);
}
DEV short8 ald16(const unsigned short* p) {
  unsigned long long lo = __hip_atomic_load((const unsigned long long*)p,     __ATOMIC_RELAXED, AGENT);
  unsigned long long hi = __hip_atomic_load((const unsigned long long*)p + 1, __ATOMIC_RELAXED, AGENT);
  union { unsigned long long q[2]; short8 s; } u;
  u.q[0] = lo; u.q[1] = hi;
  return u.s;
}

// custom grid barrier: monotonic counter, release arrive + relaxed tight spin
DEV void bar(unsigned* ctr, unsigned target) {
  __syncthreads();   // drains vmcnt: all this wg's LLC stores have landed
  if (threadIdx.x == 0) {
    __hip_atomic_fetch_add(ctr, 1u, __ATOMIC_RELEASE, AGENT);
    while (__hip_atomic_load(ctr, __ATOMIC_RELAXED, AGENT) < target)
      __builtin_amdgcn_s_sleep(1);
  }
  __syncthreads();
}

__global__ void zero_u32(unsigned* p) { if (threadIdx.x == 0) *p = 0; }

// ---------------------------------------------------------------------------
// fp32 -> bf16 convert, 4 elems/thread
__global__ __launch_bounds__(256) void cvt4(const float* __restrict__ in,
                                            unsigned short* __restrict__ out, int n4) {
  const int idx = blockIdx.x * 256 + threadIdx.x;
  if (idx >= n4) return;
  float4 v = ((const float4*)in)[idx];
  ushort4v o = { f2bf(v.x), f2bf(v.y), f2bf(v.z), f2bf(v.w) };
  ((ushort4v*)out)[idx] = o;
}

// ---------------------------------------------------------------------------
// Gather X[row] = [emb(kw_{i+1}) | emb(lw_i)] as bf16, row = i*32+b
__global__ __launch_bounds__(256) void gatherx(const float* __restrict__ emb,
                                               const int* __restrict__ targets,
                                               const int* __restrict__ tkws,
                                               unsigned short* __restrict__ X) {
  const int row = blockIdx.x;
  const int i = row >> 5, b = row & 31;
  const int t = threadIdx.x;
  const int kw = tkws[b * 64 + i + 1];
  const int lw = targets[b * 64 + i];
  const float4* src = (t < 128) ? (const float4*)(emb + (size_t)kw * 512)
                                : (const float4*)(emb + (size_t)lw * 512);
  const int c = t & 127;
  float4 v = src[c];
  ushort4v o = { f2bf(v.x), f2bf(v.y), f2bf(v.z), f2bf(v.w) };
  ((ushort4v*)(X + (size_t)row * 1024))[(t < 128 ? 0 : 128) + c] = o;
}

// ---------------------------------------------------------------------------
// C = A[M,1024] * B[N,1024]^T, 128x128 tile, BK=32, bf16 MFMA 16x16x32.
// EPI=0: store fp32 C (ldc = ldc_or_nvt).
// EPI=1: add bias, per-row (max, sum-exp) over this 128-col tile -> partials.
template <int EPI>
__global__ __launch_bounds__(256, 1) void gemm_bt(
    const unsigned short* __restrict__ A,
    const unsigned short* __restrict__ B,
    float* __restrict__ out,
    const float* __restrict__ bias,
    int ldc_or_nvt) {
  __shared__ __align__(16) unsigned short As[128 * 32];
  __shared__ __align__(16) unsigned short Bs[128 * 32];
  __shared__ float ms[2][128][2];
  const int tid = threadIdx.x;
  const int w = tid >> 6, lane = tid & 63;
  const int r4 = lane >> 2, c4 = lane & 3;
  const int m0 = blockIdx.x * 128, n0 = blockIdx.y * 128;
  const int m_off = (w & 1) * 64, n_off = (w >> 1) * 64;
  const int lrow = lane & 15, lk = (lane >> 4) * 8;

  const unsigned short* Ab = A + (size_t)(m0 + w * 16 + r4) * 1024 + c4 * 8;
  const unsigned short* Bb = B + (size_t)(n0 + w * 16 + r4) * 1024 + c4 * 8;

  float4v acc[4][4] = {};

  for (int k0 = 0; k0 < 1024; k0 += 32) {
    gl2lds16(Ab + k0,             &As[w * 512]);
    gl2lds16(Ab + 64 * 1024 + k0, &As[2048 + w * 512]);
    gl2lds16(Bb + k0,             &Bs[w * 512]);
    gl2lds16(Bb + 64 * 1024 + k0, &Bs[2048 + w * 512]);
    __syncthreads();
    short8 af[4], bfr[4];
#pragma unroll
    for (int t = 0; t < 4; t++) {
      af[t]  = *(const short8*)&As[(m_off + t * 16 + lrow) * 32 + lk];
      bfr[t] = *(const short8*)&Bs[(n_off + t * 16 + lrow) * 32 + lk];
    }
#pragma unroll
    for (int mt = 0; mt < 4; mt++)
#pragma unroll
      for (int nt = 0; nt < 4; nt++)
        acc[mt][nt] = __builtin_amdgcn_mfma_f32_16x16x32_bf16(af[mt], bfr[nt], acc[mt][nt], 0, 0, 0);
    __syncthreads();
  }

  if constexpr (EPI == 0) {
    const int ldc = ldc_or_nvt;
#pragma unroll
    for (int mt = 0; mt < 4; mt++) {
      const int gr = m0 + m_off + mt * 16 + (lane >> 4) * 4;
#pragma unroll
      for (int nt = 0; nt < 4; nt++) {
        const int gc = n0 + n_off + nt * 16 + lrow;
#pragma unroll
        for (int rg = 0; rg < 4; rg++)
          out[(size_t)(gr + rg) * ldc + gc] = acc[mt][nt][rg];
      }
    }
  } else {
    const int nvt = ldc_or_nvt;
    float b4[4];
#pragma unroll
    for (int nt = 0; nt < 4; nt++) b4[nt] = bias[n0 + n_off + nt * 16 + lrow];
#pragma unroll
    for (int mt = 0; mt < 4; mt++) {
#pragma unroll
      for (int rg = 0; rg < 4; rg++) {
        float v0 = acc[mt][0][rg] + b4[0];
        float v1 = acc[mt][1][rg] + b4[1];
        float v2 = acc[mt][2][rg] + b4[2];
        float v3 = acc[mt][3][rg] + b4[3];
        float mx = fmaxf(fmaxf(v0, v1), fmaxf(v2, v3));
#pragma unroll
        for (int d = 1; d < 16; d <<= 1) mx = fmaxf(mx, __shfl_xor(mx, d, 64));
        float s = __expf(v0 - mx) + __expf(v1 - mx) + __expf(v2 - mx) + __expf(v3 - mx);
#pragma unroll
        for (int d = 1; d < 16; d <<= 1) s += __shfl_xor(s, d, 64);
        if ((lane & 15) == 0) {
          int r = m_off + mt * 16 + (lane >> 4) * 4 + rg;
          ms[w >> 1][r][0] = mx;
          ms[w >> 1][r][1] = s;
        }
      }
    }
    __syncthreads();
    if (tid < 128) {
      float m1 = ms[0][tid][0], s1 = ms[0][tid][1];
      float m2 = ms[1][tid][0], s2 = ms[1][tid][1];
      float M = fmaxf(m1, m2);
      float S = s1 * __expf(m1 - M) + s2 * __expf(m2 - M);
      ((float2*)out)[(size_t)(m0 + tid) * nvt + blockIdx.y] = make_float2(M, S);
    }
  }
}

// ---------------------------------------------------------------------------
// Cooperative recurrence: 64 wgs x 256 thr, wg owns 16 hidden cols (jb..jb+15).
// Cross-wg state (h_bf/sent_bf/WH) moves via LLC write-through stores and
// LLC-bypass loads; custom atomic-counter barrier instead of grid.sync().
__global__ __launch_bounds__(256, 1) void recur_kernel(
    const float* __restrict__ Gi,
    const unsigned short* __restrict__ WhhB,
    const unsigned short* __restrict__ sWihB,
    const unsigned short* __restrict__ sWhhB,
    unsigned short* __restrict__ h_bf,
    unsigned short* __restrict__ sent_bf,
    unsigned short* __restrict__ WH,
    const float* __restrict__ w_bih, const float* __restrict__ w_bhh,
    const float* __restrict__ s_bih, const float* __restrict__ s_bhh,
    const int* __restrict__ targets,
    const float* __restrict__ sent_state,
    unsigned* __restrict__ ctr) {
  __shared__ float Cred[2][32][48];
  __shared__ float hsl[32][16];
  __shared__ float ssl[32][16];
  __shared__ float whsl[32][16];
  const int tid = threadIdx.x;
  const int lane = tid & 63, wv = tid >> 6;
  const int khalf = wv >> 1, mtile = wv & 1;
  const int jb = blockIdx.x * 16;
  const int bb = mtile * 16 + (lane & 15);
  const int kb = khalf * 512 + (lane >> 4) * 8;
  const int b0 = (tid * 2) >> 4, j0 = (tid * 2) & 15;   // this thread's 2 elems
  unsigned epoch = 0;

  {
    float v0 = sent_state[b0 * 1024 + jb + j0];
    float v1 = sent_state[b0 * 1024 + jb + j0 + 1];
    hsl[b0][j0] = v0; hsl[b0][j0 + 1] = v1;
    ssl[b0][j0] = v0; ssl[b0][j0 + 1] = v1;
    unsigned pv = (unsigned)f2bf(v0) | ((unsigned)f2bf(v1) << 16);
    ast32(&h_bf[b0 * 1024 + jb + j0], pv);
    ast32(&sent_bf[b0 * 1024 + jb + j0], pv);
  }
  epoch++; bar(ctr, epoch * 64);

  for (int i = 0; i < 63; i++) {
    const bool anyeos = __any(targets[(lane & 31) * 64 + i + 1] == 1);

    float4v acc[3] = {};
#pragma unroll
    for (int ks = 0; ks < 16; ks++) {
      short8 a = ald16(&h_bf[bb * 1024 + kb + ks * 32]);
#pragma unroll
      for (int g = 0; g < 3; g++) {
        short8 b8 = *(const short8*)&WhhB[(size_t)(g * 1024 + jb + (lane & 15)) * 1024 + kb + ks * 32];
        acc[g] = __builtin_amdgcn_mfma_f32_16x16x32_bf16(a, b8, acc[g], 0, 0, 0);
      }
    }
#pragma unroll
    for (int g = 0; g < 3; g++)
#pragma unroll
      for (int rg = 0; rg < 4; rg++)
        Cred[khalf][mtile * 16 + (lane >> 4) * 4 + rg][g * 16 + (lane & 15)] = acc[g][rg];
    __syncthreads();

    float wh2[2];
#pragma unroll
    for (int u = 0; u < 2; u++) {
      const int b = b0, jj = j0 + u;
      const int row = i * 32 + b;
      float ghr = Cred[0][b][jj]      + Cred[1][b][jj]      + w_bhh[jb + jj];
      float ghz = Cred[0][b][16 + jj] + Cred[1][b][16 + jj] + w_bhh[1024 + jb + jj];
      float ghn = Cred[0][b][32 + jj] + Cred[1][b][32 + jj] + w_bhh[2048 + jb + jj];
      float gir = Gi[(size_t)row * 3072 + jb + jj]        + w_bih[jb + jj];
      float giz = Gi[(size_t)row * 3072 + 1024 + jb + jj] + w_bih[1024 + jb + jj];
      float gin = Gi[(size_t)row * 3072 + 2048 + jb + jj] + w_bih[2048 + jb + jj];
      float r = 1.f / (1.f + __expf(-(gir + ghr)));
      float z = 1.f / (1.f + __expf(-(giz + ghz)));
      float n = tanhf(gin + r * ghn);
      float wh = (1.f - z) * n + z * hsl[b][jj];
      whsl[b][jj] = wh;
      wh2[u] = wh;
    }
    {
      unsigned pv = (unsigned)f2bf(wh2[0]) | ((unsigned)f2bf(wh2[1]) << 16);
      ast32(&WH[(size_t)(i * 32 + b0) * 1024 + jb + j0], pv);
    }

    if (!anyeos) {
      hsl[b0][j0] = wh2[0]; hsl[b0][j0 + 1] = wh2[1];
      unsigned pv = (unsigned)f2bf(wh2[0]) | ((unsigned)f2bf(wh2[1]) << 16);
      ast32(&h_bf[b0 * 1024 + jb + j0], pv);
      epoch++; bar(ctr, epoch * 64);
    } else {
      epoch++; bar(ctr, epoch * 64);   // WH visible grid-wide
      // gi_s = wh @ sWih^T
      float4v acc2[3] = {};
#pragma unroll
      for (int ks = 0; ks < 16; ks++) {
        short8 a = ald16(&WH[(size_t)(i * 32 + bb) * 1024 + kb + ks * 32]);
#pragma unroll
        for (int g = 0; g < 3; g++) {
          short8 b8 = *(const short8*)&sWihB[(size_t)(g * 1024 + jb + (lane & 15)) * 1024 + kb + ks * 32];
          acc2[g] = __builtin_amdgcn_mfma_f32_16x16x32_bf16(a, b8, acc2[g], 0, 0, 0);
        }
      }
#pragma unroll
      for (int g = 0; g < 3; g++)
#pragma unroll
        for (int rg = 0; rg < 4; rg++)
          Cred[khalf][mtile * 16 + (lane >> 4) * 4 + rg][g * 16 + (lane & 15)] = acc2[g][rg];
      __syncthreads();
      float gis[2][3];
#pragma unroll
      for (int u = 0; u < 2; u++) {
        const int jj = j0 + u;
#pragma unroll
        for (int g = 0; g < 3; g++)
          gis[u][g] = Cred[0][b0][g * 16 + jj] + Cred[1][b0][g * 16 + jj] + s_bih[g * 1024 + jb + jj];
      }
      __syncthreads();
      // gh_s = sent @ sWhh^T
      float4v acc3[3] = {};
#pragma unroll
      for (int ks = 0; ks < 16; ks++) {
        short8 a = ald16(&sent_bf[bb * 1024 + kb + ks * 32]);
#pragma unroll
        for (int g = 0; g < 3; g++) {
          short8 b8 = *(const short8*)&sWhhB[(size_t)(g * 1024 + jb + (lane & 15)) * 1024 + kb + ks * 32];
          acc3[g] = __builtin_amdgcn_mfma_f32_16x16x32_bf16(a, b8, acc3[g], 0, 0, 0);
        }
      }
#pragma unroll
      for (int g = 0; g < 3; g++)
#pragma unroll
        for (int rg = 0; rg < 4; rg++)
          Cred[khalf][mtile * 16 + (lane >> 4) * 4 + rg][g * 16 + (lane & 15)] = acc3[g][rg];
      __syncthreads();
      float ns2[2], nw2[2];
#pragma unroll
      for (int u = 0; u < 2; u++) {
        const int jj = j0 + u;
        float shr = Cred[0][b0][jj]      + Cred[1][b0][jj]      + s_bhh[jb + jj];
        float shz = Cred[0][b0][16 + jj] + Cred[1][b0][16 + jj] + s_bhh[1024 + jb + jj];
        float shn = Cred[0][b0][32 + jj] + Cred[1][b0][32 + jj] + s_bhh[2048 + jb + jj];
        float r = 1.f / (1.f + __expf(-(gis[u][0] + shr)));
        float z = 1.f / (1.f + __expf(-(gis[u][1] + shz)));
        float n = tanhf(gis[u][2] + r * shn);
        float s_old = ssl[b0][jj];
        float tmp = (1.f - z) * n + z * s_old;
        bool m = (targets[b0 * 64 + i + 1] == 1);
        ns2[u] = m ? tmp : s_old;
        nw2[u] = m ? tmp : whsl[b0][jj];
        ssl[b0][jj] = ns2[u];
        hsl[b0][jj] = nw2[u];
      }
      unsigned pvs = (unsigned)f2bf(ns2[0]) | ((unsigned)f2bf(ns2[1]) << 16);
      unsigned pvh = (unsigned)f2bf(nw2[0]) | ((unsigned)f2bf(nw2[1]) << 16);
      ast32(&sent_bf[b0 * 1024 + jb + j0], pvs);
      ast32(&h_bf[b0 * 1024 + jb + j0], pvh);
      epoch++; bar(ctr, epoch * 64);
    }
  }
}

// ---------------------------------------------------------------------------
// Per row: y = WH[row].outW[tgt] + out_b[tgt]; lse from 250 (m,s) partials;
// term = valid * (y - lse). One wave per row.
__global__ __launch_bounds__(256) void row_loss(
    const unsigned short* __restrict__ WH,
    const unsigned short* __restrict__ outWb,
    const float* __restrict__ out_b,
    const int* __restrict__ targets,
    const int* __restrict__ targets_len,
    const float2* __restrict__ partials,
    float* __restrict__ term) {
  const int wv = threadIdx.x >> 6, lane = threadIdx.x & 63;
  const int row = blockIdx.x * 4 + wv;
  const int b = row & 31, i = row >> 5;
  const int tgt = targets[b * 64 + i + 1];
  const short8* a8 = (const short8*)(WH + (size_t)row * 1024);
  const short8* w8 = (const short8*)(outWb + (size_t)tgt * 1024);
  float s = 0.f;
#pragma unroll
  for (int c = 0; c < 2; c++) {
    short8 av = a8[lane + 64 * c];
    short8 wv8 = w8[lane + 64 * c];
#pragma unroll
    for (int j = 0; j < 8; j++)
      s += bf2f((unsigned short)av[j]) * bf2f((unsigned short)wv8[j]);
  }
#pragma unroll
  for (int d = 32; d; d >>= 1) s += __shfl_xor(s, d, 64);

  float m = -1e30f, ssum = 0.f;
  for (int vt = lane; vt < 250; vt += 64) {
    float2 pp = partials[(size_t)row * 250 + vt];
    float nm = fmaxf(m, pp.x);
    ssum = ssum * __expf(m - nm) + pp.y * __expf(pp.x - nm);
    m = nm;
  }
#pragma unroll
  for (int d = 32; d; d >>= 1) {
    float om = __shfl_xor(m, d, 64);
    float os = __shfl_xor(ssum, d, 64);
    float nm = fmaxf(m, om);
    ssum = ssum * __expf(m - nm) + os * __expf(om - nm);
    m = nm;
  }
  if (lane == 0) {
    float y = s + out_b[tgt];
    float lse = m + logf(ssum);
    float valid = (targets_len[b] > i + 1) ? 1.f : 0.f;
    term[row] = valid * (y - lse);
  }
}

__global__ void final_sum(const float* __restrict__ term, float* __restrict__ out) {
  __shared__ float red[256];
  float s = 0.f;
  for (int r = threadIdx.x; r < 2016; r += 256) s += term[r];
  red[threadIdx.x] = s;
  __syncthreads();
  for (int st = 128; st; st >>= 1) {
    if ((int)threadIdx.x < st) red[threadIdx.x] += red[threadIdx.x + st];
    __syncthreads();
  }
  if (threadIdx.x == 0) out[0] = -red[0];
}

// ---------------------------------------------------------------------------
extern "C" void kernel_launch(void* const* d_in, const int* in_sizes, int n_in,
                              void* d_out, int out_size, void* d_ws, size_t ws_size,
                              hipStream_t stream) {
  const int*   targets     = (const int*)d_in[0];
  const int*   targets_kws = (const int*)d_in[1];
  const float* sent_state  = (const float*)d_in[2];
  const int*   targets_len = (const int*)d_in[3];
  const float* emb_W       = (const float*)d_in[4];
  const float* w_Wih       = (const float*)d_in[5];
  const float* w_Whh       = (const float*)d_in[6];
  const float* w_bih       = (const float*)d_in[7];
  const float* w_bhh       = (const float*)d_in[8];
  const float* s_Wih       = (const float*)d_in[9];
  const float* s_Whh       = (const float*)d_in[10];
  const float* s_bih       = (const float*)d_in[11];
  const float* s_bhh       = (const float*)d_in[12];
  const float* out_W       = (const float*)d_in[13];
  const float* out_b       = (const float*)d_in[14];

  char* base = (char*)d_ws;
  size_t off = 0;
  auto alloc = [&](size_t bytes) -> void* {
    void* r = base + off;
    off += (bytes + 255) & ~(size_t)255;
    return r;
  };
  unsigned short* outWb   = (unsigned short*)alloc(32000ull * 1024 * 2);
  unsigned short* WihB    = (unsigned short*)alloc(3072ull * 1024 * 2);
  unsigned short* WhhB    = (unsigned short*)alloc(3072ull * 1024 * 2);
  unsigned short* sWihB   = (unsigned short*)alloc(3072ull * 1024 * 2);
  unsigned short* sWhhB   = (unsigned short*)alloc(3072ull * 1024 * 2);
  unsigned short* Xb      = (unsigned short*)alloc(2048ull * 1024 * 2);
  float*          Gi      = (float*)alloc(2048ull * 3072 * 4);
  unsigned short* WH      = (unsigned short*)alloc(2048ull * 1024 * 2);
  unsigned short* h_bf    = (unsigned short*)alloc(32ull * 1024 * 2);
  unsigned short* sent_bf = (unsigned short*)alloc(32ull * 1024 * 2);
  float2*         parts   = (float2*)alloc(2048ull * 250 * 8);
  float*          term    = (float*)alloc(2048ull * 4);
  unsigned*       ctr     = (unsigned*)alloc(256);

  zero_u32<<<1, 64, 0, stream>>>(ctr);
  cvt4<<<32000, 256, 0, stream>>>(out_W, outWb, 8192000);
  cvt4<<<3072, 256, 0, stream>>>(w_Wih, WihB, 786432);
  cvt4<<<3072, 256, 0, stream>>>(w_Whh, WhhB, 786432);
  cvt4<<<3072, 256, 0, stream>>>(s_Wih, sWihB, 786432);
  cvt4<<<3072, 256, 0, stream>>>(s_Whh, sWhhB, 786432);
  gatherx<<<2016, 256, 0, stream>>>(emb_W, targets, targets_kws, Xb);
  gemm_bt<0><<<dim3(16, 24), 256, 0, stream>>>(Xb, WihB, Gi, nullptr, 3072);

  void* kargs[] = { (void*)&Gi, (void*)&WhhB, (void*)&sWihB, (void*)&sWhhB,
                    (void*)&h_bf, (void*)&sent_bf, (void*)&WH,
                    (void*)&w_bih, (void*)&w_bhh, (void*)&s_bih, (void*)&s_bhh,
                    (void*)&targets, (void*)&sent_state, (void*)&ctr };
  hipLaunchCooperativeKernel((void*)recur_kernel, dim3(64), dim3(256), kargs, 0, stream);

  gemm_bt<1><<<dim3(16, 250), 256, 0, stream>>>(WH, outWb, (float*)parts, out_b, 250);
  row_loss<<<504, 256, 0, stream>>>(WH, outWb, out_b, targets, targets_len, parts, term);
  final_sum<<<1, 256, 0, stream>>>(term, (float*)d_out);
}

// Round 3
// 962.519 us; speedup vs baseline: 2.1901x; 1.1043x over previous
//
#include <hip/hip_runtime.h>
#include <hip/hip_cooperative_groups.h>

namespace cg = cooperative_groups;

typedef __attribute__((ext_vector_type(8))) short short8;
typedef __attribute__((ext_vector_type(4))) float float4v;
typedef __attribute__((ext_vector_type(4))) unsigned short ushort4v;

#define DEV __device__ __forceinline__
#define AGENT __HIP_MEMORY_SCOPE_AGENT

DEV unsigned short f2bf(float f) {
  union { float f; unsigned u; } v; v.f = f;
  unsigned r = v.u + 0x7fffu + ((v.u >> 16) & 1u);
  return (unsigned short)(r >> 16);
}
DEV float bf2f(unsigned short h) {
  union { unsigned u; float f; } v; v.u = ((unsigned)h) << 16;
  return v.f;
}

// async global->LDS, 16B per lane; LDS dest is wave-uniform base + lane*16
DEV void gl2lds16(const void* g, void* l) {
  __builtin_amdgcn_global_load_lds(
      (const __attribute__((address_space(1))) void*)g,
      (__attribute__((address_space(3))) void*)l, 16, 0, 0);
}

// --- cross-workgroup data movement: LLC write-through / bypass ------------
DEV void ast32(unsigned short* p, unsigned v) {
  __hip_atomic_store((unsigned*)p, v, __ATOMIC_RELAXED, AGENT);
}
DEV short8 ald16(const unsigned short* p) {
  unsigned long long lo = __hip_atomic_load((const unsigned long long*)p,     __ATOMIC_RELAXED, AGENT);
  unsigned long long hi = __hip_atomic_load((const unsigned long long*)p + 1, __ATOMIC_RELAXED, AGENT);
  union { unsigned long long q[2]; short8 s; } u;
  u.q[0] = lo; u.q[1] = hi;
  return u.s;
}

// Grid barrier without RMW: wg stores flags[wg]=epoch (own cacheline);
// wave0's 64 lanes each poll one wg's flag, __all across the wave.
// __syncthreads before = vmcnt(0) drain (stores are write-through, at LLC).
DEV void bar(unsigned* flags, unsigned epoch) {
  __syncthreads();
  if (threadIdx.x < 64) {
    const int lane = threadIdx.x;
    if (lane == 0)
      __hip_atomic_store(&flags[blockIdx.x * 32], epoch, __ATOMIC_RELAXED, AGENT);
    bool ok = false;
    do {
      ok = ok || (__hip_atomic_load(&flags[lane * 32], __ATOMIC_RELAXED, AGENT) >= epoch);
    } while (!__all(ok));
  }
  __syncthreads();
}

__global__ __launch_bounds__(256) void zero_flags(unsigned* p, int n) {
  int i = blockIdx.x * 256 + threadIdx.x;
  if (i < n) p[i] = 0;
}

// ---------------------------------------------------------------------------
// fp32 -> bf16 convert, 4 elems/thread
__global__ __launch_bounds__(256) void cvt4(const float* __restrict__ in,
                                            unsigned short* __restrict__ out, int n4) {
  const int idx = blockIdx.x * 256 + threadIdx.x;
  if (idx >= n4) return;
  float4 v = ((const float4*)in)[idx];
  ushort4v o = { f2bf(v.x), f2bf(v.y), f2bf(v.z), f2bf(v.w) };
  ((ushort4v*)out)[idx] = o;
}

// ---------------------------------------------------------------------------
// Gather X[row] = [emb(kw_{i+1}) | emb(lw_i)] as bf16, row = i*32+b
__global__ __launch_bounds__(256) void gatherx(const float* __restrict__ emb,
                                               const int* __restrict__ targets,
                                               const int* __restrict__ tkws,
                                               unsigned short* __restrict__ X) {
  const int row = blockIdx.x;
  const int i = row >> 5, b = row & 31;
  const int t = threadIdx.x;
  const int kw = tkws[b * 64 + i + 1];
  const int lw = targets[b * 64 + i];
  const float4* src = (t < 128) ? (const float4*)(emb + (size_t)kw * 512)
                                : (const float4*)(emb + (size_t)lw * 512);
  const int c = t & 127;
  float4 v = src[c];
  ushort4v o = { f2bf(v.x), f2bf(v.y), f2bf(v.z), f2bf(v.w) };
  ((ushort4v*)(X + (size_t)row * 1024))[(t < 128 ? 0 : 128) + c] = o;
}

// ---------------------------------------------------------------------------
// C = A[M,1024] * B[N,1024]^T, 128x128 tile, BK=32, bf16 MFMA 16x16x32.
// EPI=0: store fp32 C (ldc = ldc_or_nvt).
// EPI=1: add bias, per-row (max, sum-exp) over this 128-col tile -> partials.
template <int EPI>
__global__ __launch_bounds__(256, 1) void gemm_bt(
    const unsigned short* __restrict__ A,
    const unsigned short* __restrict__ B,
    float* __restrict__ out,
    const float* __restrict__ bias,
    int ldc_or_nvt) {
  __shared__ __align__(16) unsigned short As[128 * 32];
  __shared__ __align__(16) unsigned short Bs[128 * 32];
  __shared__ float ms[2][128][2];
  const int tid = threadIdx.x;
  const int w = tid >> 6, lane = tid & 63;
  const int r4 = lane >> 2, c4 = lane & 3;
  const int m0 = blockIdx.x * 128, n0 = blockIdx.y * 128;
  const int m_off = (w & 1) * 64, n_off = (w >> 1) * 64;
  const int lrow = lane & 15, lk = (lane >> 4) * 8;

  const unsigned short* Ab = A + (size_t)(m0 + w * 16 + r4) * 1024 + c4 * 8;
  const unsigned short* Bb = B + (size_t)(n0 + w * 16 + r4) * 1024 + c4 * 8;

  float4v acc[4][4] = {};

  for (int k0 = 0; k0 < 1024; k0 += 32) {
    gl2lds16(Ab + k0,             &As[w * 512]);
    gl2lds16(Ab + 64 * 1024 + k0, &As[2048 + w * 512]);
    gl2lds16(Bb + k0,             &Bs[w * 512]);
    gl2lds16(Bb + 64 * 1024 + k0, &Bs[2048 + w * 512]);
    __syncthreads();
    short8 af[4], bfr[4];
#pragma unroll
    for (int t = 0; t < 4; t++) {
      af[t]  = *(const short8*)&As[(m_off + t * 16 + lrow) * 32 + lk];
      bfr[t] = *(const short8*)&Bs[(n_off + t * 16 + lrow) * 32 + lk];
    }
#pragma unroll
    for (int mt = 0; mt < 4; mt++)
#pragma unroll
      for (int nt = 0; nt < 4; nt++)
        acc[mt][nt] = __builtin_amdgcn_mfma_f32_16x16x32_bf16(af[mt], bfr[nt], acc[mt][nt], 0, 0, 0);
    __syncthreads();
  }

  if constexpr (EPI == 0) {
    const int ldc = ldc_or_nvt;
#pragma unroll
    for (int mt = 0; mt < 4; mt++) {
      const int gr = m0 + m_off + mt * 16 + (lane >> 4) * 4;
#pragma unroll
      for (int nt = 0; nt < 4; nt++) {
        const int gc = n0 + n_off + nt * 16 + lrow;
#pragma unroll
        for (int rg = 0; rg < 4; rg++)
          out[(size_t)(gr + rg) * ldc + gc] = acc[mt][nt][rg];
      }
    }
  } else {
    const int nvt = ldc_or_nvt;
    float b4[4];
#pragma unroll
    for (int nt = 0; nt < 4; nt++) b4[nt] = bias[n0 + n_off + nt * 16 + lrow];
#pragma unroll
    for (int mt = 0; mt < 4; mt++) {
#pragma unroll
      for (int rg = 0; rg < 4; rg++) {
        float v0 = acc[mt][0][rg] + b4[0];
        float v1 = acc[mt][1][rg] + b4[1];
        float v2 = acc[mt][2][rg] + b4[2];
        float v3 = acc[mt][3][rg] + b4[3];
        float mx = fmaxf(fmaxf(v0, v1), fmaxf(v2, v3));
#pragma unroll
        for (int d = 1; d < 16; d <<= 1) mx = fmaxf(mx, __shfl_xor(mx, d, 64));
        float s = __expf(v0 - mx) + __expf(v1 - mx) + __expf(v2 - mx) + __expf(v3 - mx);
#pragma unroll
        for (int d = 1; d < 16; d <<= 1) s += __shfl_xor(s, d, 64);
        if ((lane & 15) == 0) {
          int r = m_off + mt * 16 + (lane >> 4) * 4 + rg;
          ms[w >> 1][r][0] = mx;
          ms[w >> 1][r][1] = s;
        }
      }
    }
    __syncthreads();
    if (tid < 128) {
      float m1 = ms[0][tid][0], s1 = ms[0][tid][1];
      float m2 = ms[1][tid][0], s2 = ms[1][tid][1];
      float M = fmaxf(m1, m2);
      float S = s1 * __expf(m1 - M) + s2 * __expf(m2 - M);
      ((float2*)out)[(size_t)(m0 + tid) * nvt + blockIdx.y] = make_float2(M, S);
    }
  }
}

// ---------------------------------------------------------------------------
// Cooperative recurrence: 64 wgs x 256 thr, wg owns 16 hidden cols (jb..jb+15).
// Whh wg-slice LDS-resident (XOR-swizzled 16B chunks). h/sent double-buffered
// (fixes cross-wg overwrite race). Flag-array barrier (no RMW, no wbl2).
__global__ __launch_bounds__(256, 1) void recur_kernel(
    const float* __restrict__ Gi,
    const unsigned short* __restrict__ WhhB,
    const unsigned short* __restrict__ sWihB,
    const unsigned short* __restrict__ sWhhB,
    unsigned short* __restrict__ h_bf,      // 2 x 32768 u16
    unsigned short* __restrict__ sent_bf,   // 2 x 32768 u16
    unsigned short* __restrict__ WH,
    const float* __restrict__ w_bih, const float* __restrict__ w_bhh,
    const float* __restrict__ s_bih, const float* __restrict__ s_bhh,
    const int* __restrict__ targets,
    const float* __restrict__ sent_state,
    unsigned* __restrict__ flags) {
  __shared__ __align__(16) unsigned short WhhS[48 * 1024];   // 96 KB
  __shared__ float Cred[2][32][49];
  __shared__ float hsl[32][16];
  __shared__ float ssl[32][16];
  __shared__ float whsl[32][16];
  const int tid = threadIdx.x;
  const int lane = tid & 63, wv = tid >> 6;
  const int khalf = wv >> 1, mtile = wv & 1;
  const int jb = blockIdx.x * 16;
  const int lr = lane & 15;
  const int bb = mtile * 16 + lr;
  const int kb = khalf * 512 + (lane >> 4) * 8;
  const int cb = kb >> 3;          // 16B-chunk base within row
  const int swz = lr & 7;
  const int b0 = (tid * 2) >> 4, j0 = (tid * 2) & 15;
  unsigned epoch = 0;
  int scur = 0;

  // ---- one-time: Whh wg-slice -> LDS, XOR-swizzled 16B chunks ----
  for (int idx = tid; idx < 6144; idx += 256) {
    const int R = idx >> 7, c = idx & 127;     // R = g*16+rr, c = chunk
    const int g = R >> 4, rr = R & 15;
    short8 v = *(const short8*)&WhhB[((size_t)(g * 1024 + jb + rr)) * 1024 + c * 8];
    *(short8*)&WhhS[(R * 128 + (c ^ (rr & 7))) * 8] = v;
  }

  // ---- one-time: per-step "any EOS" bitmask (grid-uniform) ----
  unsigned long long eosmask;
  {
    bool e = false;
    if (lane < 63)
      for (int b = 0; b < 32; b++) e |= (targets[b * 64 + lane + 1] == 1);
    eosmask = __ballot(e);
  }

  // ---- one-time: biases for this thread's 2 elements ----
  float bi[2][3], bh[2][3];
#pragma unroll
  for (int u = 0; u < 2; u++)
#pragma unroll
    for (int g = 0; g < 3; g++) {
      bi[u][g] = w_bih[g * 1024 + jb + j0 + u];
      bh[u][g] = w_bhh[g * 1024 + jb + j0 + u];
    }

  // ---- init state, publish to buffer 0 ----
  {
    float v0 = sent_state[b0 * 1024 + jb + j0];
    float v1 = sent_state[b0 * 1024 + jb + j0 + 1];
    hsl[b0][j0] = v0; hsl[b0][j0 + 1] = v1;
    ssl[b0][j0] = v0; ssl[b0][j0 + 1] = v1;
    unsigned pv = (unsigned)f2bf(v0) | ((unsigned)f2bf(v1) << 16);
    ast32(&h_bf[b0 * 1024 + jb + j0], pv);
    ast32(&sent_bf[b0 * 1024 + jb + j0], pv);
  }

  // ---- Gi prefetch for step 0 ----
  float2 gp[3];
  {
    const float* p = Gi + (size_t)b0 * 3072 + jb + j0;
    gp[0] = *(const float2*)(p);
    gp[1] = *(const float2*)(p + 1024);
    gp[2] = *(const float2*)(p + 2048);
  }

  epoch++; bar(flags, epoch);

  for (int i = 0; i < 63; i++) {
    const unsigned short* hr = h_bf + (i & 1) * 32768;
    unsigned short*       hw = h_bf + ((i + 1) & 1) * 32768;
    const bool anyeos = (eosmask >> i) & 1;

    // gh = h @ Whh^T  (A from LLC, B from LDS)
    float4v acc[3] = {};
#pragma unroll
    for (int ks = 0; ks < 16; ks++) {
      short8 a = ald16(&hr[bb * 1024 + kb + ks * 32]);
#pragma unroll
      for (int g = 0; g < 3; g++) {
        short8 b8 = *(const short8*)&WhhS[((g * 16 + lr) * 128 + ((cb + ks * 4) ^ swz)) * 8];
        acc[g] = __builtin_amdgcn_mfma_f32_16x16x32_bf16(a, b8, acc[g], 0, 0, 0);
      }
    }
#pragma unroll
    for (int g = 0; g < 3; g++)
#pragma unroll
      for (int rg = 0; rg < 4; rg++)
        Cred[khalf][mtile * 16 + (lane >> 4) * 4 + rg][g * 16 + lr] = acc[g][rg];
    __syncthreads();

    float wh2[2];
#pragma unroll
    for (int u = 0; u < 2; u++) {
      const int jj = j0 + u;
      float ghr = Cred[0][b0][jj]      + Cred[1][b0][jj]      + bh[u][0];
      float ghz = Cred[0][b0][16 + jj] + Cred[1][b0][16 + jj] + bh[u][1];
      float ghn = Cred[0][b0][32 + jj] + Cred[1][b0][32 + jj] + bh[u][2];
      float gir = ((float*)&gp[0])[u] + bi[u][0];
      float giz = ((float*)&gp[1])[u] + bi[u][1];
      float gin = ((float*)&gp[2])[u] + bi[u][2];
      float r = 1.f / (1.f + __expf(-(gir + ghr)));
      float z = 1.f / (1.f + __expf(-(giz + ghz)));
      float n = tanhf(gin + r * ghn);
      float wh = (1.f - z) * n + z * hsl[b0][jj];
      whsl[b0][jj] = wh;
      wh2[u] = wh;
    }
    {
      unsigned pv = (unsigned)f2bf(wh2[0]) | ((unsigned)f2bf(wh2[1]) << 16);
      ast32(&WH[(size_t)(i * 32 + b0) * 1024 + jb + j0], pv);
    }

    // Gi prefetch for next step (independent of barrier)
    if (i < 62) {
      const float* p = Gi + (size_t)((i + 1) * 32 + b0) * 3072 + jb + j0;
      gp[0] = *(const float2*)(p);
      gp[1] = *(const float2*)(p + 1024);
      gp[2] = *(const float2*)(p + 2048);
    }

    if (!anyeos) {
      hsl[b0][j0] = wh2[0]; hsl[b0][j0 + 1] = wh2[1];
      unsigned pv = (unsigned)f2bf(wh2[0]) | ((unsigned)f2bf(wh2[1]) << 16);
      ast32(&hw[b0 * 1024 + jb + j0], pv);
      epoch++; bar(flags, epoch);
    } else {
      epoch++; bar(flags, epoch);   // WH[i] visible grid-wide
      const unsigned short* sr = sent_bf + scur * 32768;
      unsigned short*       sw = sent_bf + (scur ^ 1) * 32768;
      // gi_s = wh @ sWih^T
      float4v acc2[3] = {};
#pragma unroll
      for (int ks = 0; ks < 16; ks++) {
        short8 a = ald16(&WH[(size_t)(i * 32 + bb) * 1024 + kb + ks * 32]);
#pragma unroll
        for (int g = 0; g < 3; g++) {
          short8 b8 = *(const short8*)&sWihB[(size_t)(g * 1024 + jb + lr) * 1024 + kb + ks * 32];
          acc2[g] = __builtin_amdgcn_mfma_f32_16x16x32_bf16(a, b8, acc2[g], 0, 0, 0);
        }
      }
#pragma unroll
      for (int g = 0; g < 3; g++)
#pragma unroll
        for (int rg = 0; rg < 4; rg++)
          Cred[khalf][mtile * 16 + (lane >> 4) * 4 + rg][g * 16 + lr] = acc2[g][rg];
      __syncthreads();
      float gis[2][3];
#pragma unroll
      for (int u = 0; u < 2; u++) {
        const int jj = j0 + u;
#pragma unroll
        for (int g = 0; g < 3; g++)
          gis[u][g] = Cred[0][b0][g * 16 + jj] + Cred[1][b0][g * 16 + jj] + s_bih[g * 1024 + jb + jj];
      }
      __syncthreads();
      // gh_s = sent @ sWhh^T
      float4v acc3[3] = {};
#pragma unroll
      for (int ks = 0; ks < 16; ks++) {
        short8 a = ald16(&sr[bb * 1024 + kb + ks * 32]);
#pragma unroll
        for (int g = 0; g < 3; g++) {
          short8 b8 = *(const short8*)&sWhhB[(size_t)(g * 1024 + jb + lr) * 1024 + kb + ks * 32];
          acc3[g] = __builtin_amdgcn_mfma_f32_16x16x32_bf16(a, b8, acc3[g], 0, 0, 0);
        }
      }
#pragma unroll
      for (int g = 0; g < 3; g++)
#pragma unroll
        for (int rg = 0; rg < 4; rg++)
          Cred[khalf][mtile * 16 + (lane >> 4) * 4 + rg][g * 16 + lr] = acc3[g][rg];
      __syncthreads();
      float ns2[2], nw2[2];
#pragma unroll
      for (int u = 0; u < 2; u++) {
        const int jj = j0 + u;
        float shr = Cred[0][b0][jj]      + Cred[1][b0][jj]      + s_bhh[jb + jj];
        float shz = Cred[0][b0][16 + jj] + Cred[1][b0][16 + jj] + s_bhh[1024 + jb + jj];
        float shn = Cred[0][b0][32 + jj] + Cred[1][b0][32 + jj] + s_bhh[2048 + jb + jj];
        float r = 1.f / (1.f + __expf(-(gis[u][0] + shr)));
        float z = 1.f / (1.f + __expf(-(gis[u][1] + shz)));
        float n = tanhf(gis[u][2] + r * shn);
        float s_old = ssl[b0][jj];
        float tmp = (1.f - z) * n + z * s_old;
        bool m = (targets[b0 * 64 + i + 1] == 1);
        ns2[u] = m ? tmp : s_old;
        nw2[u] = m ? tmp : whsl[b0][jj];
        ssl[b0][jj] = ns2[u];
        hsl[b0][jj] = nw2[u];
      }
      unsigned pvs = (unsigned)f2bf(ns2[0]) | ((unsigned)f2bf(ns2[1]) << 16);
      unsigned pvh = (unsigned)f2bf(nw2[0]) | ((unsigned)f2bf(nw2[1]) << 16);
      ast32(&sw[b0 * 1024 + jb + j0], pvs);
      ast32(&hw[b0 * 1024 + jb + j0], pvh);
      scur ^= 1;
      epoch++; bar(flags, epoch);
    }
  }
}

// ---------------------------------------------------------------------------
// Per row: y = WH[row].outW[tgt] + out_b[tgt]; lse from 250 (m,s) partials;
// term = valid * (y - lse). One wave per row.
__global__ __launch_bounds__(256) void row_loss(
    const unsigned short* __restrict__ WH,
    const unsigned short* __restrict__ outWb,
    const float* __restrict__ out_b,
    const int* __restrict__ targets,
    const int* __restrict__ targets_len,
    const float2* __restrict__ partials,
    float* __restrict__ term) {
  const int wv = threadIdx.x >> 6, lane = threadIdx.x & 63;
  const int row = blockIdx.x * 4 + wv;
  const int b = row & 31, i = row >> 5;
  const int tgt = targets[b * 64 + i + 1];
  const short8* a8 = (const short8*)(WH + (size_t)row * 1024);
  const short8* w8 = (const short8*)(outWb + (size_t)tgt * 1024);
  float s = 0.f;
#pragma unroll
  for (int c = 0; c < 2; c++) {
    short8 av = a8[lane + 64 * c];
    short8 wv8 = w8[lane + 64 * c];
#pragma unroll
    for (int j = 0; j < 8; j++)
      s += bf2f((unsigned short)av[j]) * bf2f((unsigned short)wv8[j]);
  }
#pragma unroll
  for (int d = 32; d; d >>= 1) s += __shfl_xor(s, d, 64);

  float m = -1e30f, ssum = 0.f;
  for (int vt = lane; vt < 250; vt += 64) {
    float2 pp = partials[(size_t)row * 250 + vt];
    float nm = fmaxf(m, pp.x);
    ssum = ssum * __expf(m - nm) + pp.y * __expf(pp.x - nm);
    m = nm;
  }
#pragma unroll
  for (int d = 32; d; d >>= 1) {
    float om = __shfl_xor(m, d, 64);
    float os = __shfl_xor(ssum, d, 64);
    float nm = fmaxf(m, om);
    ssum = ssum * __expf(m - nm) + os * __expf(om - nm);
    m = nm;
  }
  if (lane == 0) {
    float y = s + out_b[tgt];
    float lse = m + logf(ssum);
    float valid = (targets_len[b] > i + 1) ? 1.f : 0.f;
    term[row] = valid * (y - lse);
  }
}

__global__ void final_sum(const float* __restrict__ term, float* __restrict__ out) {
  __shared__ float red[256];
  float s = 0.f;
  for (int r = threadIdx.x; r < 2016; r += 256) s += term[r];
  red[threadIdx.x] = s;
  __syncthreads();
  for (int st = 128; st; st >>= 1) {
    if ((int)threadIdx.x < st) red[threadIdx.x] += red[threadIdx.x + st];
    __syncthreads();
  }
  if (threadIdx.x == 0) out[0] = -red[0];
}

// ---------------------------------------------------------------------------
extern "C" void kernel_launch(void* const* d_in, const int* in_sizes, int n_in,
                              void* d_out, int out_size, void* d_ws, size_t ws_size,
                              hipStream_t stream) {
  const int*   targets     = (const int*)d_in[0];
  const int*   targets_kws = (const int*)d_in[1];
  const float* sent_state  = (const float*)d_in[2];
  const int*   targets_len = (const int*)d_in[3];
  const float* emb_W       = (const float*)d_in[4];
  const float* w_Wih       = (const float*)d_in[5];
  const float* w_Whh       = (const float*)d_in[6];
  const float* w_bih       = (const float*)d_in[7];
  const float* w_bhh       = (const float*)d_in[8];
  const float* s_Wih       = (const float*)d_in[9];
  const float* s_Whh       = (const float*)d_in[10];
  const float* s_bih       = (const float*)d_in[11];
  const float* s_bhh       = (const float*)d_in[12];
  const float* out_W       = (const float*)d_in[13];
  const float* out_b       = (const float*)d_in[14];

  char* base = (char*)d_ws;
  size_t off = 0;
  auto alloc = [&](size_t bytes) -> void* {
    void* r = base + off;
    off += (bytes + 255) & ~(size_t)255;
    return r;
  };
  unsigned short* outWb   = (unsigned short*)alloc(32000ull * 1024 * 2);
  unsigned short* WihB    = (unsigned short*)alloc(3072ull * 1024 * 2);
  unsigned short* WhhB    = (unsigned short*)alloc(3072ull * 1024 * 2);
  unsigned short* sWihB   = (unsigned short*)alloc(3072ull * 1024 * 2);
  unsigned short* sWhhB   = (unsigned short*)alloc(3072ull * 1024 * 2);
  unsigned short* Xb      = (unsigned short*)alloc(2048ull * 1024 * 2);
  float*          Gi      = (float*)alloc(2048ull * 3072 * 4);
  unsigned short* WH      = (unsigned short*)alloc(2048ull * 1024 * 2);
  unsigned short* h_bf    = (unsigned short*)alloc(2 * 32ull * 1024 * 2);
  unsigned short* sent_bf = (unsigned short*)alloc(2 * 32ull * 1024 * 2);
  float2*         parts   = (float2*)alloc(2048ull * 250 * 8);
  float*          term    = (float*)alloc(2048ull * 4);
  unsigned*       flags   = (unsigned*)alloc(64 * 32 * 4);

  zero_flags<<<8, 256, 0, stream>>>(flags, 2048);
  cvt4<<<32000, 256, 0, stream>>>(out_W, outWb, 8192000);
  cvt4<<<3072, 256, 0, stream>>>(w_Wih, WihB, 786432);
  cvt4<<<3072, 256, 0, stream>>>(w_Whh, WhhB, 786432);
  cvt4<<<3072, 256, 0, stream>>>(s_Wih, sWihB, 786432);
  cvt4<<<3072, 256, 0, stream>>>(s_Whh, sWhhB, 786432);
  gatherx<<<2016, 256, 0, stream>>>(emb_W, targets, targets_kws, Xb);
  gemm_bt<0><<<dim3(16, 24), 256, 0, stream>>>(Xb, WihB, Gi, nullptr, 3072);

  void* kargs[] = { (void*)&Gi, (void*)&WhhB, (void*)&sWihB, (void*)&sWhhB,
                    (void*)&h_bf, (void*)&sent_bf, (void*)&WH,
                    (void*)&w_bih, (void*)&w_bhh, (void*)&s_bih, (void*)&s_bhh,
                    (void*)&targets, (void*)&sent_state, (void*)&flags };
  hipLaunchCooperativeKernel((void*)recur_kernel, dim3(64), dim3(256), kargs, 0, stream);

  gemm_bt<1><<<dim3(16, 250), 256, 0, stream>>>(WH, outWb, (float*)parts, out_b, 250);
  row_loss<<<504, 256, 0, stream>>>(WH, outWb, out_b, targets, targets_len, parts, term);
  final_sum<<<1, 256, 0, stream>>>(term, (float*)d_out);
}